// Round 1
// baseline (5064.449 us; speedup 1.0000x reference)
//
#include <hip/hip_runtime.h>
#include <hip/hip_bf16.h>
#include <stdint.h>

// Problem dims (fixed by reference)
#define Bq    8192
#define Hh    8
#define Dd    16
#define Kk    16
#define Nn    4096
#define DFf   16
#define ROWS  (Bq*Hh)          // 65536
#define COLS  (Dd*Kk)          // 256
#define EPSF  1e-6f

typedef unsigned long long u64;
typedef unsigned int u32;

// ---------- helpers ----------
__device__ __forceinline__ float dot4(float4 a, float4 b) {
    return fmaf(a.x, b.x, fmaf(a.y, b.y, fmaf(a.z, b.z, a.w * b.w)));
}
__device__ __forceinline__ float wave_sum(float v) {
    // 64-lane butterfly; result broadcast to all lanes
    #pragma unroll
    for (int m = 32; m > 0; m >>= 1) v += __shfl_xor(v, m, 64);
    return v;
}
// monotone key: larger float -> larger key (total order incl. negatives)
__device__ __forceinline__ u32 f32_sortable(float f) {
    u32 u = __float_as_uint(f);
    return (u & 0x80000000u) ? ~u : (u | 0x80000000u);
}

// ---------- kernel 0+xx: init best[] and compute xx[r] = sum(xf^2) ----------
__global__ __launch_bounds__(256) void k_rownorm_init(const float* __restrict__ X,
                                                      float* __restrict__ xx,
                                                      u64* __restrict__ best) {
    int r    = blockIdx.x * 4 + (threadIdx.x >> 6);
    int lane = threadIdx.x & 63;
    float4 v = *reinterpret_cast<const float4*>(X + (size_t)r * COLS + lane * 4);
    float s = wave_sum(v.x*v.x + v.y*v.y + v.z*v.z + v.w*v.w);
    if (lane == 0) { xx[r] = s; best[r] = ~0ull; }
}

// ---------- kernel 1: codebook = W_o * (gate(W_i * fc)) , plus |cb|^2 ----------
__global__ __launch_bounds__(256) void k_codebook(const float* __restrict__ fc,
                                                  const float* __restrict__ Wi,
                                                  const float* __restrict__ Wo,
                                                  float* __restrict__ CB,
                                                  float* __restrict__ cbn) {
    int n = blockIdx.x, tid = threadIdx.x;
    int o = tid >> 4, k = tid & 15;
    __shared__ float fcs[256], wis[256], wos[256], hs[256], sq[256];
    fcs[tid] = fc[(size_t)n * 256 + tid];
    wis[tid] = Wi[tid];
    wos[tid] = Wo[tid];
    __syncthreads();
    float hp = 0.f;
    #pragma unroll
    for (int i = 0; i < 16; ++i) hp = fmaf(wis[o*16 + i], fcs[i*16 + k], hp);
    hs[tid] = hp;
    __syncthreads();
    float h0 = hs[o * 16];            // scalar (k=0) component, pre-gate
    // jax.nn.gelu default (approximate=True, tanh form)
    float x3 = h0 * h0 * h0;
    float inner = 0.7978845608028654f * fmaf(0.044715f, x3, h0);
    float g = 0.5f * h0 * (1.f + tanhf(inner));
    float hg = hp * g;
    __syncthreads();
    hs[tid] = hg;
    __syncthreads();
    float cv = 0.f;
    #pragma unroll
    for (int i = 0; i < 16; ++i) cv = fmaf(wos[o*16 + i], hs[i*16 + k], cv);
    CB[(size_t)n * 256 + tid] = cv;
    sq[tid] = cv * cv;
    __syncthreads();
    #pragma unroll
    for (int st = 128; st > 0; st >>= 1) {
        if (tid < st) sq[tid] += sq[tid + st];
        __syncthreads();
    }
    if (tid == 0) cbn[n] = sq[0];
}

// ---------- kernel 2: distance GEMM (fp32) + fused row-argmin ----------
// Tile 64 rows x 64 codes, 256 threads (16x16), 4x4 micro-tile, K-step 32.
#define BM 64
#define BN 64
#define KB 32
#define LDP 36   // padded LDS stride (float4-aligned, bank-spread)

__global__ __launch_bounds__(256) void k_dist_argmin(const float* __restrict__ X,
                                                     const float* __restrict__ CB,
                                                     const float* __restrict__ cbn,
                                                     const float* __restrict__ xx,
                                                     u64* __restrict__ best) {
    __shared__ float a_s[BM][LDP];
    __shared__ float b_s[BN][LDP];
    __shared__ u64 red[64][16];

    int tid = threadIdx.x;
    int bn  = blockIdx.x;   // code tile 0..63 (fast-varying -> CB stays hot in L2)
    int bm  = blockIdx.y;   // row tile 0..1023
    int tx  = tid & 15, ty = tid >> 4;

    const float* Xb = X  + (size_t)bm * BM * COLS;
    const float* Cb = CB + (size_t)bn * BN * COLS;

    float acc[4][4] = {};

    for (int kk = 0; kk < COLS; kk += KB) {
        #pragma unroll
        for (int u = 0; u < 2; ++u) {
            int g = tid + u * 256;     // 0..511
            int m = g >> 3;            // row 0..63
            int q = g & 7;             // float4 slot 0..7
            float4 va = *reinterpret_cast<const float4*>(Xb + (size_t)m * COLS + kk + q * 4);
            float4 vb = *reinterpret_cast<const float4*>(Cb + (size_t)m * COLS + kk + q * 4);
            *reinterpret_cast<float4*>(&a_s[m][q * 4]) = va;
            *reinterpret_cast<float4*>(&b_s[m][q * 4]) = vb;
        }
        __syncthreads();
        #pragma unroll
        for (int p = 0; p < KB; p += 4) {
            float4 av[4], bv[4];
            #pragma unroll
            for (int r = 0; r < 4; ++r) av[r] = *reinterpret_cast<const float4*>(&a_s[ty*4 + r][p]);
            #pragma unroll
            for (int c = 0; c < 4; ++c) bv[c] = *reinterpret_cast<const float4*>(&b_s[tx*4 + c][p]);
            #pragma unroll
            for (int r = 0; r < 4; ++r)
                #pragma unroll
                for (int c = 0; c < 4; ++c) {
                    acc[r][c] = fmaf(av[r].x, bv[c].x, acc[r][c]);
                    acc[r][c] = fmaf(av[r].y, bv[c].y, acc[r][c]);
                    acc[r][c] = fmaf(av[r].z, bv[c].z, acc[r][c]);
                    acc[r][c] = fmaf(av[r].w, bv[c].w, acc[r][c]);
                }
        }
        __syncthreads();
    }

    // epilogue: d2 = (xx - 2*dot) + cbn, replicating the reference expression
    // tree rounding; pack (sortable_d2<<32 | idx) so ties pick the lowest index.
    float xxv[4], cbnv[4];
    #pragma unroll
    for (int r = 0; r < 4; ++r) xxv[r]  = xx [bm * BM + ty*4 + r];
    #pragma unroll
    for (int c = 0; c < 4; ++c) cbnv[c] = cbn[bn * BN + tx*4 + c];

    #pragma unroll
    for (int r = 0; r < 4; ++r) {
        u64 bl = ~0ull;
        #pragma unroll
        for (int c = 0; c < 4; ++c) {
            float t  = fmaf(-2.f, acc[r][c], xxv[r]);  // round(xx - 2*dot)
            float d2 = t + cbnv[c];                    // round(+cbn)
            u64 pk = ((u64)f32_sortable(d2) << 32) | (u32)(bn * BN + tx*4 + c);
            bl = pk < bl ? pk : bl;
        }
        red[ty*4 + r][tx] = bl;
    }
    __syncthreads();
    if (tid < 64) {
        u64 b = red[tid][0];
        #pragma unroll
        for (int t = 1; t < 16; ++t) { u64 v = red[tid][t]; b = v < b ? v : b; }
        atomicMin(&best[bm * BM + tid], b);
    }
}

// ---------- kernel 3: gather e, Householder STE, write e and s ----------
__global__ __launch_bounds__(256) void k_epilogue(const float* __restrict__ X,
                                                  const float* __restrict__ CB,
                                                  const u64* __restrict__ best,
                                                  float* __restrict__ Eout,
                                                  float* __restrict__ Sout) {
    int r    = blockIdx.x * 4 + (threadIdx.x >> 6);
    int lane = threadIdx.x & 63;
    int idx  = (int)(best[r] & 0xffffffffull);

    float4 xv = *reinterpret_cast<const float4*>(X  + (size_t)r   * COLS + lane * 4);
    float4 ev = *reinterpret_cast<const float4*>(CB + (size_t)idx * COLS + lane * 4);

    float xn2 = wave_sum(dot4(xv, xv));
    float en2 = wave_sum(dot4(ev, ev));
    float xn = sqrtf(xn2), en = sqrtf(en2);
    float invx = 1.f / fmaxf(xn, EPSF);
    float inve = 1.f / fmaxf(en, EPSF);

    float4 xd, ed, sd0;
    xd.x = xv.x*invx; xd.y = xv.y*invx; xd.z = xv.z*invx; xd.w = xv.w*invx;
    ed.x = ev.x*inve; ed.y = ev.y*inve; ed.z = ev.z*inve; ed.w = ev.w*inve;
    sd0.x = xd.x+ed.x; sd0.y = xd.y+ed.y; sd0.z = xd.z+ed.z; sd0.w = xd.w+ed.w;

    float sdn2 = wave_sum(dot4(sd0, sd0));
    float p1   = wave_sum(dot4(sd0, xv));   // (sd0 . xf)
    float p2   = wave_sum(dot4(xd,  xv));   // (xd  . xf)
    float invs = 1.f / fmaxf(sqrtf(sdn2), EPSF);

    float csd = -2.f * invs * invs * p1;    // r = xf - 2*sd*(sd.xf) + 2*ed*(xd.xf)
    float ced =  2.f * p2;
    float4 rr;
    rr.x = fmaf(csd, sd0.x, fmaf(ced, ed.x, xv.x));
    rr.y = fmaf(csd, sd0.y, fmaf(ced, ed.y, xv.y));
    rr.z = fmaf(csd, sd0.z, fmaf(ced, ed.z, xv.z));
    rr.w = fmaf(csd, sd0.w, fmaf(ced, ed.w, xv.w));
    float sc = en * invx;
    float4 sv; sv.x = rr.x*sc; sv.y = rr.y*sc; sv.z = rr.z*sc; sv.w = rr.w*sc;

    *reinterpret_cast<float4*>(Eout + (size_t)r * COLS + lane * 4) = ev;
    *reinterpret_cast<float4*>(Sout + (size_t)r * COLS + lane * 4) = sv;
}

// ---------- launcher ----------
extern "C" void kernel_launch(void* const* d_in, const int* in_sizes, int n_in,
                              void* d_out, int out_size, void* d_ws, size_t ws_size,
                              hipStream_t stream) {
    const float* x  = (const float*)d_in[0];   // (8192, 128, 16) == (65536, 256) flat
    const float* fc = (const float*)d_in[1];   // (4096, 16, 16)
    const float* Wi = (const float*)d_in[2];   // (16, 16)
    const float* Wo = (const float*)d_in[3];   // (16, 16)

    // workspace layout
    u64*   best = (u64*)d_ws;                                        // 65536*8   = 512 KiB
    float* CBws = (float*)((char*)d_ws + (size_t)ROWS * 8);          // 4096*256*4 = 4 MiB
    float* cbn  = (float*)((char*)CBws + (size_t)Nn * COLS * 4);     // 4096*4
    float* xx   = (float*)((char*)cbn + (size_t)Nn * 4);             // 65536*4

    float* Eout = (float*)d_out;
    float* Sout = Eout + (size_t)ROWS * COLS;

    k_rownorm_init<<<ROWS / 4, 256, 0, stream>>>(x, xx, best);
    k_codebook<<<Nn, 256, 0, stream>>>(fc, Wi, Wo, CBws, cbn);
    k_dist_argmin<<<dim3(Nn / BN, ROWS / BM), 256, 0, stream>>>(x, CBws, cbn, xx, best);
    k_epilogue<<<ROWS / 4, 256, 0, stream>>>(x, CBws, best, Eout, Sout);
}

// Round 2
// 2158.057 us; speedup vs baseline: 2.3468x; 2.3468x over previous
//
#include <hip/hip_runtime.h>
#include <hip/hip_bf16.h>
#include <stdint.h>

// Problem dims (fixed by reference)
#define Bq    8192
#define Hh    8
#define Dd    16
#define Kk    16
#define Nn    4096
#define DFf   16
#define ROWS  (Bq*Hh)          // 65536
#define COLS  (Dd*Kk)          // 256
#define EPSF  1e-6f

typedef unsigned long long u64;
typedef unsigned int u32;

// ---------- helpers ----------
__device__ __forceinline__ float dot4(float4 a, float4 b) {
    return fmaf(a.x, b.x, fmaf(a.y, b.y, fmaf(a.z, b.z, a.w * b.w)));
}
__device__ __forceinline__ float wave_sum(float v) {
    // 64-lane butterfly; result broadcast to all lanes
    #pragma unroll
    for (int m = 32; m > 0; m >>= 1) v += __shfl_xor(v, m, 64);
    return v;
}
// monotone key: larger float -> larger key (total order incl. negatives)
__device__ __forceinline__ u32 f32_sortable(float f) {
    u32 u = __float_as_uint(f);
    return (u & 0x80000000u) ? ~u : (u | 0x80000000u);
}

// ---------- kernel 0+xx: init best[] and compute xx[r] = sum(xf^2) ----------
__global__ __launch_bounds__(256) void k_rownorm_init(const float* __restrict__ X,
                                                      float* __restrict__ xx,
                                                      u64* __restrict__ best) {
    int r    = blockIdx.x * 4 + (threadIdx.x >> 6);
    int lane = threadIdx.x & 63;
    float4 v = *reinterpret_cast<const float4*>(X + (size_t)r * COLS + lane * 4);
    float s = wave_sum(v.x*v.x + v.y*v.y + v.z*v.z + v.w*v.w);
    if (lane == 0) { xx[r] = s; best[r] = ~0ull; }
}

// ---------- kernel 1: codebook = W_o * (gate(W_i * fc)) , plus |cb|^2 ----------
__global__ __launch_bounds__(256) void k_codebook(const float* __restrict__ fc,
                                                  const float* __restrict__ Wi,
                                                  const float* __restrict__ Wo,
                                                  float* __restrict__ CB,
                                                  float* __restrict__ cbn) {
    int n = blockIdx.x, tid = threadIdx.x;
    int o = tid >> 4, k = tid & 15;
    __shared__ float fcs[256], wis[256], wos[256], hs[256], sq[256];
    fcs[tid] = fc[(size_t)n * 256 + tid];
    wis[tid] = Wi[tid];
    wos[tid] = Wo[tid];
    __syncthreads();
    float hp = 0.f;
    #pragma unroll
    for (int i = 0; i < 16; ++i) hp = fmaf(wis[o*16 + i], fcs[i*16 + k], hp);
    hs[tid] = hp;
    __syncthreads();
    float h0 = hs[o * 16];            // scalar (k=0) component, pre-gate
    // jax.nn.gelu default (approximate=True, tanh form)
    float x3 = h0 * h0 * h0;
    float inner = 0.7978845608028654f * fmaf(0.044715f, x3, h0);
    float g = 0.5f * h0 * (1.f + tanhf(inner));
    float hg = hp * g;
    __syncthreads();
    hs[tid] = hg;
    __syncthreads();
    float cv = 0.f;
    #pragma unroll
    for (int i = 0; i < 16; ++i) cv = fmaf(wos[o*16 + i], hs[i*16 + k], cv);
    CB[(size_t)n * 256 + tid] = cv;
    sq[tid] = cv * cv;
    __syncthreads();
    #pragma unroll
    for (int st = 128; st > 0; st >>= 1) {
        if (tid < st) sq[tid] += sq[tid + st];
        __syncthreads();
    }
    if (tid == 0) cbn[n] = sq[0];
}

// ---------- kernel 2: distance GEMM (fp32) + fused row-argmin ----------
// Tile 64 rows x 64 codes, 256 threads (16x16), 4x4 micro-tile, K-step 32.
// STRIDED fragment mapping (m = ty + 16r, n = tx + 16c): B-fragment lane
// address stride becomes 1 row = 36 floats -> bank stride 4 -> 16 lanes
// spread over all eight 4-bank windows (2-way aliasing = free, m136).
// LDP=36 keeps rows 16B-aligned so ds_read_b128 survives.
#define BM 64
#define BN 64
#define KB 32
#define LDP 36

__global__ __launch_bounds__(256) void k_dist_argmin(const float* __restrict__ X,
                                                     const float* __restrict__ CB,
                                                     const float* __restrict__ cbn,
                                                     const float* __restrict__ xx,
                                                     u64* __restrict__ best) {
    __shared__ float a_s[BM][LDP];
    __shared__ float b_s[BN][LDP];
    __shared__ u64 red[64][16];

    int tid = threadIdx.x;
    int bn  = blockIdx.x;   // code tile 0..63 (fast-varying -> CB stays hot in L2)
    int bm  = blockIdx.y;   // row tile 0..1023
    int tx  = tid & 15, ty = tid >> 4;

    const float* Xb = X  + (size_t)bm * BM * COLS;
    const float* Cb = CB + (size_t)bn * BN * COLS;

    float acc[4][4] = {};

    for (int kk = 0; kk < COLS; kk += KB) {
        #pragma unroll
        for (int u = 0; u < 2; ++u) {
            int g = tid + u * 256;     // 0..511
            int m = g >> 3;            // row 0..63
            int q = g & 7;             // float4 slot 0..7
            float4 va = *reinterpret_cast<const float4*>(Xb + (size_t)m * COLS + kk + q * 4);
            float4 vb = *reinterpret_cast<const float4*>(Cb + (size_t)m * COLS + kk + q * 4);
            *reinterpret_cast<float4*>(&a_s[m][q * 4]) = va;
            *reinterpret_cast<float4*>(&b_s[m][q * 4]) = vb;
        }
        __syncthreads();
        #pragma unroll
        for (int p = 0; p < KB; p += 4) {
            float4 av[4], bv[4];
            #pragma unroll
            for (int r = 0; r < 4; ++r) av[r] = *reinterpret_cast<const float4*>(&a_s[ty + 16*r][p]);
            #pragma unroll
            for (int c = 0; c < 4; ++c) bv[c] = *reinterpret_cast<const float4*>(&b_s[tx + 16*c][p]);
            #pragma unroll
            for (int r = 0; r < 4; ++r)
                #pragma unroll
                for (int c = 0; c < 4; ++c) {
                    acc[r][c] = fmaf(av[r].x, bv[c].x, acc[r][c]);
                    acc[r][c] = fmaf(av[r].y, bv[c].y, acc[r][c]);
                    acc[r][c] = fmaf(av[r].z, bv[c].z, acc[r][c]);
                    acc[r][c] = fmaf(av[r].w, bv[c].w, acc[r][c]);
                }
        }
        __syncthreads();
    }

    // epilogue: d2 = (xx - 2*dot) + cbn, replicating the reference expression
    // tree rounding; pack (sortable_d2<<32 | idx) so ties pick the lowest index.
    float xxv[4], cbnv[4];
    #pragma unroll
    for (int r = 0; r < 4; ++r) xxv[r]  = xx [bm * BM + ty + 16*r];
    #pragma unroll
    for (int c = 0; c < 4; ++c) cbnv[c] = cbn[bn * BN + tx + 16*c];

    #pragma unroll
    for (int r = 0; r < 4; ++r) {
        u64 bl = ~0ull;
        #pragma unroll
        for (int c = 0; c < 4; ++c) {
            float t  = fmaf(-2.f, acc[r][c], xxv[r]);  // round(xx - 2*dot)
            float d2 = t + cbnv[c];                    // round(+cbn)
            u64 pk = ((u64)f32_sortable(d2) << 32) | (u32)(bn * BN + tx + 16*c);
            bl = pk < bl ? pk : bl;
        }
        red[ty + 16*r][tx] = bl;
    }
    __syncthreads();
    if (tid < 64) {
        u64 b = red[tid][0];
        #pragma unroll
        for (int t = 1; t < 16; ++t) { u64 v = red[tid][t]; b = v < b ? v : b; }
        atomicMin(&best[bm * BM + tid], b);
    }
}

// ---------- kernel 3: gather e, Householder STE, write e and s ----------
__global__ __launch_bounds__(256) void k_epilogue(const float* __restrict__ X,
                                                  const float* __restrict__ CB,
                                                  const u64* __restrict__ best,
                                                  float* __restrict__ Eout,
                                                  float* __restrict__ Sout) {
    int r    = blockIdx.x * 4 + (threadIdx.x >> 6);
    int lane = threadIdx.x & 63;
    int idx  = (int)(best[r] & 0xffffffffull);

    float4 xv = *reinterpret_cast<const float4*>(X  + (size_t)r   * COLS + lane * 4);
    float4 ev = *reinterpret_cast<const float4*>(CB + (size_t)idx * COLS + lane * 4);

    float xn2 = wave_sum(dot4(xv, xv));
    float en2 = wave_sum(dot4(ev, ev));
    float xn = sqrtf(xn2), en = sqrtf(en2);
    float invx = 1.f / fmaxf(xn, EPSF);
    float inve = 1.f / fmaxf(en, EPSF);

    float4 xd, ed, sd0;
    xd.x = xv.x*invx; xd.y = xv.y*invx; xd.z = xv.z*invx; xd.w = xv.w*invx;
    ed.x = ev.x*inve; ed.y = ev.y*inve; ed.z = ev.z*inve; ed.w = ev.w*inve;
    sd0.x = xd.x+ed.x; sd0.y = xd.y+ed.y; sd0.z = xd.z+ed.z; sd0.w = xd.w+ed.w;

    float sdn2 = wave_sum(dot4(sd0, sd0));
    float p1   = wave_sum(dot4(sd0, xv));   // (sd0 . xf)
    float p2   = wave_sum(dot4(xd,  xv));   // (xd  . xf)
    float invs = 1.f / fmaxf(sqrtf(sdn2), EPSF);

    float csd = -2.f * invs * invs * p1;    // r = xf - 2*sd*(sd.xf) + 2*ed*(xd.xf)
    float ced =  2.f * p2;
    float4 rr;
    rr.x = fmaf(csd, sd0.x, fmaf(ced, ed.x, xv.x));
    rr.y = fmaf(csd, sd0.y, fmaf(ced, ed.y, xv.y));
    rr.z = fmaf(csd, sd0.z, fmaf(ced, ed.z, xv.z));
    rr.w = fmaf(csd, sd0.w, fmaf(ced, ed.w, xv.w));
    float sc = en * invx;
    float4 sv; sv.x = rr.x*sc; sv.y = rr.y*sc; sv.z = rr.z*sc; sv.w = rr.w*sc;

    *reinterpret_cast<float4*>(Eout + (size_t)r * COLS + lane * 4) = ev;
    *reinterpret_cast<float4*>(Sout + (size_t)r * COLS + lane * 4) = sv;
}

// ---------- launcher ----------
extern "C" void kernel_launch(void* const* d_in, const int* in_sizes, int n_in,
                              void* d_out, int out_size, void* d_ws, size_t ws_size,
                              hipStream_t stream) {
    const float* x  = (const float*)d_in[0];   // (8192, 128, 16) == (65536, 256) flat
    const float* fc = (const float*)d_in[1];   // (4096, 16, 16)
    const float* Wi = (const float*)d_in[2];   // (16, 16)
    const float* Wo = (const float*)d_in[3];   // (16, 16)

    // workspace layout
    u64*   best = (u64*)d_ws;                                        // 65536*8   = 512 KiB
    float* CBws = (float*)((char*)d_ws + (size_t)ROWS * 8);          // 4096*256*4 = 4 MiB
    float* cbn  = (float*)((char*)CBws + (size_t)Nn * COLS * 4);     // 4096*4
    float* xx   = (float*)((char*)cbn + (size_t)Nn * 4);             // 65536*4

    float* Eout = (float*)d_out;
    float* Sout = Eout + (size_t)ROWS * COLS;

    k_rownorm_init<<<ROWS / 4, 256, 0, stream>>>(x, xx, best);
    k_codebook<<<Nn, 256, 0, stream>>>(fc, Wi, Wo, CBws, cbn);
    k_dist_argmin<<<dim3(Nn / BN, ROWS / BM), 256, 0, stream>>>(x, CBws, cbn, xx, best);
    k_epilogue<<<ROWS / 4, 256, 0, stream>>>(x, CBws, best, Eout, Sout);
}

// Round 3
// 1213.450 us; speedup vs baseline: 4.1736x; 1.7784x over previous
//
#include <hip/hip_runtime.h>
#include <hip/hip_bf16.h>
#include <stdint.h>

// Problem dims (fixed by reference)
#define Bq    8192
#define Hh    8
#define Dd    16
#define Kk    16
#define Nn    4096
#define DFf   16
#define ROWS  (Bq*Hh)          // 65536
#define COLS  (Dd*Kk)          // 256
#define EPSF  1e-6f

typedef unsigned long long u64;
typedef unsigned int u32;
typedef __attribute__((ext_vector_type(8))) short bf16x8;
typedef __attribute__((ext_vector_type(4))) float f32x4;

// ---------- helpers ----------
__device__ __forceinline__ float dot4(float4 a, float4 b) {
    return fmaf(a.x, b.x, fmaf(a.y, b.y, fmaf(a.z, b.z, a.w * b.w)));
}
__device__ __forceinline__ float wave_sum(float v) {
    #pragma unroll
    for (int m = 32; m > 0; m >>= 1) v += __shfl_xor(v, m, 64);
    return v;
}
__device__ __forceinline__ u32 f32_sortable(float f) {
    u32 u = __float_as_uint(f);
    return (u & 0x80000000u) ? ~u : (u | 0x80000000u);
}
__device__ __forceinline__ float f32_unsortable(u32 k) {
    u32 u = (k & 0x80000000u) ? (k ^ 0x80000000u) : ~k;
    return __uint_as_float(u);
}
// pack 2 floats -> 2 bf16 (RNE, v_cvt_pk_bf16_f32); low 16 bits = a
__device__ __forceinline__ u32 pk2(float a, float b) {
    union { __hip_bfloat162 h; u32 u; } v;
    v.h = __float22bfloat162_rn(make_float2(a, b));
    return v.u;
}

// ---------- kernel 0: xx[r], init best/min1/cbn_max ----------
__global__ __launch_bounds__(256) void k_prep(const float* __restrict__ X,
                                              float* __restrict__ xx,
                                              u64* __restrict__ best,
                                              u32* __restrict__ min1,
                                              u32* __restrict__ cbn_max) {
    int r    = blockIdx.x * 4 + (threadIdx.x >> 6);
    int lane = threadIdx.x & 63;
    float4 v = *reinterpret_cast<const float4*>(X + (size_t)r * COLS + lane * 4);
    float s = wave_sum(v.x*v.x + v.y*v.y + v.z*v.z + v.w*v.w);
    if (lane == 0) { xx[r] = s; best[r] = ~0ull; min1[r] = ~0u; }
    if (blockIdx.x == 0 && threadIdx.x == 0) *cbn_max = 0u;
}

// ---------- kernel 1: codebook + |cb|^2 + max|cb|^2 ----------
__global__ __launch_bounds__(256) void k_codebook(const float* __restrict__ fc,
                                                  const float* __restrict__ Wi,
                                                  const float* __restrict__ Wo,
                                                  float* __restrict__ CB,
                                                  float* __restrict__ cbn,
                                                  u32* __restrict__ cbn_max) {
    int n = blockIdx.x, tid = threadIdx.x;
    int o = tid >> 4, k = tid & 15;
    __shared__ float fcs[256], wis[256], wos[256], hs[256], sq[256];
    fcs[tid] = fc[(size_t)n * 256 + tid];
    wis[tid] = Wi[tid];
    wos[tid] = Wo[tid];
    __syncthreads();
    float hp = 0.f;
    #pragma unroll
    for (int i = 0; i < 16; ++i) hp = fmaf(wis[o*16 + i], fcs[i*16 + k], hp);
    hs[tid] = hp;
    __syncthreads();
    float h0 = hs[o * 16];
    float x3 = h0 * h0 * h0;
    float inner = 0.7978845608028654f * fmaf(0.044715f, x3, h0);
    float g = 0.5f * h0 * (1.f + tanhf(inner));
    float hg = hp * g;
    __syncthreads();
    hs[tid] = hg;
    __syncthreads();
    float cv = 0.f;
    #pragma unroll
    for (int i = 0; i < 16; ++i) cv = fmaf(wos[o*16 + i], hs[i*16 + k], cv);
    CB[(size_t)n * 256 + tid] = cv;
    sq[tid] = cv * cv;
    __syncthreads();
    #pragma unroll
    for (int st = 128; st > 0; st >>= 1) {
        if (tid < st) sq[tid] += sq[tid + st];
        __syncthreads();
    }
    if (tid == 0) { cbn[n] = sq[0]; atomicMax(cbn_max, __float_as_uint(sq[0])); }
}

// ---------- kernel 2: bf16-MFMA screen (STAGE 0) / re-rank (STAGE 1) ----------
// 128x128 tile, 4 waves (2x2 of 64x64), 4x4 16x16x32 frags per wave, BK=64.
// LDS layout [row][8 chunks of 8 bf16], chunk XOR-swizzled by (row&7) so
// ds_write (lanes = consecutive chunks) stays contiguous and ds_read_b128
// (lanes = consecutive rows, fixed chunk) is 2-way/free (T2).
template<int STAGE>
__global__ __launch_bounds__(256) void k_screen(const float* __restrict__ X,
                                                const float* __restrict__ CB,
                                                const float* __restrict__ cbn,
                                                const float* __restrict__ xx,
                                                u32* __restrict__ min1,
                                                u64* __restrict__ best,
                                                const u32* __restrict__ cbn_max) {
    __shared__ __align__(16) short As[128 * 64];
    __shared__ __align__(16) short Bs[128 * 64];
    __shared__ float xx_s[128], cbn_s[128], thr_s[128];

    const int tid  = threadIdx.x;
    const int lane = tid & 63;
    const int w    = tid >> 6;
    const int wr   = w >> 1, wc = w & 1;
    const int bn   = blockIdx.x, bm = blockIdx.y;

    if (tid < 128) {
        float xv = xx[bm * 128 + tid];
        xx_s[tid]  = xv;
        cbn_s[tid] = cbn[bn * 128 + tid];
        if (STAGE == 1) {
            float cmax = __uint_as_float(*cbn_max);
            float mv = f32_unsortable(min1[bm * 128 + tid]);
            // delta >= 2*max approx error (bf16 input rounding), generous margin
            thr_s[tid] = mv + fmaf(0.003f, sqrtf(xv * cmax), 0.01f);
        }
    }

    f32x4 acc[4][4] = {};

    const float* Xb = X  + (size_t)bm * 128 * COLS;
    const float* Cb = CB + (size_t)bn * 128 * COLS;

    for (int kk = 0; kk < 256; kk += 64) {
        __syncthreads();
        #pragma unroll
        for (int p = 0; p < 4; ++p) {
            int u   = p * 512 + tid * 2;     // float4-pair index (fully coalesced)
            int row = u >> 4;
            int kg  = (u >> 1) & 7;          // 8-bf16 chunk within the 64-wide K slice
            const float4* sa = (const float4*)(Xb + (size_t)row * COLS + kk + kg * 8);
            const float4* sb = (const float4*)(Cb + (size_t)row * COLS + kk + kg * 8);
            float4 a0 = sa[0], a1 = sa[1], b0 = sb[0], b1 = sb[1];
            uint4 wa = { pk2(a0.x,a0.y), pk2(a0.z,a0.w), pk2(a1.x,a1.y), pk2(a1.z,a1.w) };
            uint4 wb = { pk2(b0.x,b0.y), pk2(b0.z,b0.w), pk2(b1.x,b1.y), pk2(b1.z,b1.w) };
            int swz = (kg ^ (row & 7)) << 3;
            *(uint4*)&As[row * 64 + swz] = wa;
            *(uint4*)&Bs[row * 64 + swz] = wb;
        }
        __syncthreads();
        #pragma unroll
        for (int ks = 0; ks < 2; ++ks) {
            bf16x8 af[4], bfv[4];
            int kgl = ks * 4 + (lane >> 4);
            #pragma unroll
            for (int mi = 0; mi < 4; ++mi) {
                int row = wr * 64 + mi * 16 + (lane & 15);
                af[mi] = *(const bf16x8*)&As[row * 64 + ((kgl ^ (row & 7)) << 3)];
            }
            #pragma unroll
            for (int ni = 0; ni < 4; ++ni) {
                int row = wc * 64 + ni * 16 + (lane & 15);
                bfv[ni] = *(const bf16x8*)&Bs[row * 64 + ((kgl ^ (row & 7)) << 3)];
            }
            #pragma unroll
            for (int mi = 0; mi < 4; ++mi)
                #pragma unroll
                for (int ni = 0; ni < 4; ++ni)
                    acc[mi][ni] = __builtin_amdgcn_mfma_f32_16x16x32_bf16(
                        af[mi], bfv[ni], acc[mi][ni], 0, 0, 0);
        }
    }

    // acc[mi][ni][rg] -> row_local = wr*64+mi*16+(lane>>4)*4+rg, col_local = wc*64+ni*16+(lane&15)
    if (STAGE == 0) {
        #pragma unroll
        for (int mi = 0; mi < 4; ++mi) {
            #pragma unroll
            for (int rg = 0; rg < 4; ++rg) {
                int rl = wr * 64 + mi * 16 + (lane >> 4) * 4 + rg;
                float xxv = xx_s[rl];
                float m = 1e30f;
                #pragma unroll
                for (int ni = 0; ni < 4; ++ni) {
                    float d2a = fmaf(-2.f, acc[mi][ni][rg], xxv)
                              + cbn_s[wc * 64 + ni * 16 + (lane & 15)];
                    m = fminf(m, d2a);
                }
                #pragma unroll
                for (int d = 1; d < 16; d <<= 1) m = fminf(m, __shfl_xor(m, d, 64));
                if ((lane & 15) == 0) atomicMin(&min1[bm * 128 + rl], f32_sortable(m));
            }
        }
    } else {
        #pragma unroll
        for (int mi = 0; mi < 4; ++mi) {
            #pragma unroll
            for (int rg = 0; rg < 4; ++rg) {
                int rl = wr * 64 + mi * 16 + (lane >> 4) * 4 + rg;
                float xxv = xx_s[rl];
                float thr = thr_s[rl];
                #pragma unroll
                for (int ni = 0; ni < 4; ++ni) {
                    int cl = wc * 64 + ni * 16 + (lane & 15);
                    float d2a = fmaf(-2.f, acc[mi][ni][rg], xxv) + cbn_s[cl];
                    if (d2a <= thr) {   // rare: exact fp32 re-rank, R2's expression tree
                        int row = bm * 128 + rl;
                        int col = bn * 128 + cl;
                        const float4* xp = (const float4*)(X  + (size_t)row * COLS);
                        const float4* cp = (const float4*)(CB + (size_t)col * COLS);
                        float d = 0.f;
                        #pragma unroll 8
                        for (int q = 0; q < 64; ++q) {
                            float4 a = xp[q], b = cp[q];
                            d = fmaf(a.x, b.x, d); d = fmaf(a.y, b.y, d);
                            d = fmaf(a.z, b.z, d); d = fmaf(a.w, b.w, d);
                        }
                        float d2e = fmaf(-2.f, d, xxv) + cbn_s[cl];
                        u64 pk = ((u64)f32_sortable(d2e) << 32) | (u32)col;
                        atomicMin(&best[row], pk);
                    }
                }
            }
        }
    }
}

// ---------- kernel 3: gather e, Householder STE ----------
__global__ __launch_bounds__(256) void k_epilogue(const float* __restrict__ X,
                                                  const float* __restrict__ CB,
                                                  const u64* __restrict__ best,
                                                  float* __restrict__ Eout,
                                                  float* __restrict__ Sout) {
    int r    = blockIdx.x * 4 + (threadIdx.x >> 6);
    int lane = threadIdx.x & 63;
    int idx  = (int)(best[r] & 0xffffffffull);

    float4 xv = *reinterpret_cast<const float4*>(X  + (size_t)r   * COLS + lane * 4);
    float4 ev = *reinterpret_cast<const float4*>(CB + (size_t)idx * COLS + lane * 4);

    float xn2 = wave_sum(dot4(xv, xv));
    float en2 = wave_sum(dot4(ev, ev));
    float xn = sqrtf(xn2), en = sqrtf(en2);
    float invx = 1.f / fmaxf(xn, EPSF);
    float inve = 1.f / fmaxf(en, EPSF);

    float4 xd, ed, sd0;
    xd.x = xv.x*invx; xd.y = xv.y*invx; xd.z = xv.z*invx; xd.w = xv.w*invx;
    ed.x = ev.x*inve; ed.y = ev.y*inve; ed.z = ev.z*inve; ed.w = ev.w*inve;
    sd0.x = xd.x+ed.x; sd0.y = xd.y+ed.y; sd0.z = xd.z+ed.z; sd0.w = xd.w+ed.w;

    float sdn2 = wave_sum(dot4(sd0, sd0));
    float p1   = wave_sum(dot4(sd0, xv));
    float p2   = wave_sum(dot4(xd,  xv));
    float invs = 1.f / fmaxf(sqrtf(sdn2), EPSF);

    float csd = -2.f * invs * invs * p1;
    float ced =  2.f * p2;
    float4 rr;
    rr.x = fmaf(csd, sd0.x, fmaf(ced, ed.x, xv.x));
    rr.y = fmaf(csd, sd0.y, fmaf(ced, ed.y, xv.y));
    rr.z = fmaf(csd, sd0.z, fmaf(ced, ed.z, xv.z));
    rr.w = fmaf(csd, sd0.w, fmaf(ced, ed.w, xv.w));
    float sc = en * invx;
    float4 sv; sv.x = rr.x*sc; sv.y = rr.y*sc; sv.z = rr.z*sc; sv.w = rr.w*sc;

    *reinterpret_cast<float4*>(Eout + (size_t)r * COLS + lane * 4) = ev;
    *reinterpret_cast<float4*>(Sout + (size_t)r * COLS + lane * 4) = sv;
}

// ---------- launcher ----------
extern "C" void kernel_launch(void* const* d_in, const int* in_sizes, int n_in,
                              void* d_out, int out_size, void* d_ws, size_t ws_size,
                              hipStream_t stream) {
    const float* x  = (const float*)d_in[0];
    const float* fc = (const float*)d_in[1];
    const float* Wi = (const float*)d_in[2];
    const float* Wo = (const float*)d_in[3];

    // workspace layout (~5.0 MB)
    char* ws = (char*)d_ws;
    u64*   best    = (u64*)ws;                            ws += (size_t)ROWS * 8;    // 512 KiB
    float* CBws    = (float*)ws;                          ws += (size_t)Nn * COLS * 4; // 4 MiB
    float* cbn     = (float*)ws;                          ws += (size_t)Nn * 4;
    float* xx      = (float*)ws;                          ws += (size_t)ROWS * 4;
    u32*   min1    = (u32*)ws;                            ws += (size_t)ROWS * 4;
    u32*   cbn_max = (u32*)ws;

    float* Eout = (float*)d_out;
    float* Sout = Eout + (size_t)ROWS * COLS;

    k_prep<<<ROWS / 4, 256, 0, stream>>>(x, xx, best, min1, cbn_max);
    k_codebook<<<Nn, 256, 0, stream>>>(fc, Wi, Wo, CBws, cbn, cbn_max);
    k_screen<0><<<dim3(Nn / 128, ROWS / 128), 256, 0, stream>>>(x, CBws, cbn, xx, min1, best, cbn_max);
    k_screen<1><<<dim3(Nn / 128, ROWS / 128), 256, 0, stream>>>(x, CBws, cbn, xx, min1, best, cbn_max);
    k_epilogue<<<ROWS / 4, 256, 0, stream>>>(x, CBws, best, Eout, Sout);
}

// Round 4
// 998.014 us; speedup vs baseline: 5.0745x; 1.2159x over previous
//
#include <hip/hip_runtime.h>
#include <hip/hip_bf16.h>
#include <stdint.h>

// Problem dims (fixed by reference)
#define Bq    8192
#define Hh    8
#define Dd    16
#define Kk    16
#define Nn    4096
#define DFf   16
#define ROWS  (Bq*Hh)          // 65536
#define COLS  (Dd*Kk)          // 256
#define EPSF  1e-6f

typedef unsigned long long u64;
typedef unsigned int u32;
typedef __attribute__((ext_vector_type(8))) short bf16x8;
typedef __attribute__((ext_vector_type(4))) float f32x4;

// async global->LDS, 16B per lane; LDS dest = wave-uniform base + lane*16
#define GLOAD_LDS(g, l) __builtin_amdgcn_global_load_lds( \
    (const __attribute__((address_space(1))) u32*)(g), \
    (__attribute__((address_space(3))) u32*)(l), 16, 0, 0)

// ---------- helpers ----------
__device__ __forceinline__ float dot4(float4 a, float4 b) {
    return fmaf(a.x, b.x, fmaf(a.y, b.y, fmaf(a.z, b.z, a.w * b.w)));
}
__device__ __forceinline__ float wave_sum(float v) {
    #pragma unroll
    for (int m = 32; m > 0; m >>= 1) v += __shfl_xor(v, m, 64);
    return v;
}
__device__ __forceinline__ u32 f32_sortable(float f) {
    u32 u = __float_as_uint(f);
    return (u & 0x80000000u) ? ~u : (u | 0x80000000u);
}
__device__ __forceinline__ float f32_unsortable(u32 k) {
    u32 u = (k & 0x80000000u) ? (k ^ 0x80000000u) : ~k;
    return __uint_as_float(u);
}
// pack 2 floats -> 2 bf16 (RNE); low 16 bits = a
__device__ __forceinline__ u32 pk2(float a, float b) {
    union { __hip_bfloat162 h; u32 u; } v;
    v.h = __float22bfloat162_rn(make_float2(a, b));
    return v.u;
}

// ---------- kernel 0: xx[r], X->bf16, init best/min1/cbn_max ----------
__global__ __launch_bounds__(256) void k_prep(const float* __restrict__ X,
                                              short* __restrict__ Xh,
                                              float* __restrict__ xx,
                                              u64* __restrict__ best,
                                              u32* __restrict__ min1,
                                              u32* __restrict__ cbn_max) {
    int r    = blockIdx.x * 4 + (threadIdx.x >> 6);
    int lane = threadIdx.x & 63;
    float4 v = *reinterpret_cast<const float4*>(X + (size_t)r * COLS + lane * 4);
    uint2 p; p.x = pk2(v.x, v.y); p.y = pk2(v.z, v.w);
    *reinterpret_cast<uint2*>(Xh + (size_t)r * COLS + lane * 4) = p;
    float s = wave_sum(v.x*v.x + v.y*v.y + v.z*v.z + v.w*v.w);
    if (lane == 0) { xx[r] = s; best[r] = ~0ull; min1[r] = ~0u; }
    if (blockIdx.x == 0 && threadIdx.x == 0) *cbn_max = 0u;
}

// ---------- kernel 1: codebook (fp32 + bf16) + |cb|^2 + max|cb|^2 ----------
__global__ __launch_bounds__(256) void k_codebook(const float* __restrict__ fc,
                                                  const float* __restrict__ Wi,
                                                  const float* __restrict__ Wo,
                                                  float* __restrict__ CB,
                                                  short* __restrict__ CBh,
                                                  float* __restrict__ cbn,
                                                  u32* __restrict__ cbn_max) {
    int n = blockIdx.x, tid = threadIdx.x;
    int o = tid >> 4, k = tid & 15;
    __shared__ float fcs[256], wis[256], wos[256], hs[256], sq[256];
    fcs[tid] = fc[(size_t)n * 256 + tid];
    wis[tid] = Wi[tid];
    wos[tid] = Wo[tid];
    __syncthreads();
    float hp = 0.f;
    #pragma unroll
    for (int i = 0; i < 16; ++i) hp = fmaf(wis[o*16 + i], fcs[i*16 + k], hp);
    hs[tid] = hp;
    __syncthreads();
    float h0 = hs[o * 16];
    float x3 = h0 * h0 * h0;
    float inner = 0.7978845608028654f * fmaf(0.044715f, x3, h0);
    float g = 0.5f * h0 * (1.f + tanhf(inner));
    float hg = hp * g;
    __syncthreads();
    hs[tid] = hg;
    __syncthreads();
    float cv = 0.f;
    #pragma unroll
    for (int i = 0; i < 16; ++i) cv = fmaf(wos[o*16 + i], hs[i*16 + k], cv);
    CB[(size_t)n * 256 + tid] = cv;
    { union { __hip_bfloat16 h; short s; } c; c.h = __float2bfloat16(cv);
      CBh[(size_t)n * 256 + tid] = c.s; }
    sq[tid] = cv * cv;
    __syncthreads();
    #pragma unroll
    for (int st = 128; st > 0; st >>= 1) {
        if (tid < st) sq[tid] += sq[tid + st];
        __syncthreads();
    }
    if (tid == 0) { cbn[n] = sq[0]; atomicMax(cbn_max, __float_as_uint(sq[0])); }
}

// ---------- kernel 2: bf16-MFMA screen (STAGE 0) / re-rank (STAGE 1) ----------
// 128x128 tile, 4 waves (2x2 of 64x64), 4x4 16x16x32 frags per wave, BK=64.
// bf16 inputs staged with global_load_lds (16B/lane): LDS dest linear,
// global source inverse-XOR-swizzled so ds_read_b128 with slot = kgl^(row&7)
// is conflict-free (rule #21). XCD-aware block swizzle: each XCD sweeps all
// bn for a contiguous bm band -> CBh (2 MiB) stays L2-resident per XCD.
template<int STAGE>
__global__ __launch_bounds__(256) void k_screen(const short* __restrict__ Xh,
                                                const short* __restrict__ CBh,
                                                const float* __restrict__ X,
                                                const float* __restrict__ CB,
                                                const float* __restrict__ cbn,
                                                const float* __restrict__ xx,
                                                u32* __restrict__ min1,
                                                u64* __restrict__ best,
                                                const u32* __restrict__ cbn_max) {
    __shared__ __align__(16) short As[128 * 64];
    __shared__ __align__(16) short Bs[128 * 64];
    __shared__ float xx_s[128], cbn_s[128], thr_s[128];

    const int tid  = threadIdx.x;
    const int lane = tid & 63;
    const int w    = tid >> 6;
    const int wr   = w >> 1, wc = w & 1;

    // XCD swizzle: 16384 blocks, 8 XCDs, bijective (16384 % 8 == 0)
    int bid = blockIdx.x;
    int lin = (bid & 7) * 2048 + (bid >> 3);
    int bn  = lin & 31;        // fastest within XCD chunk
    int bm  = lin >> 5;

    if (tid < 128) {
        float xv = xx[bm * 128 + tid];
        xx_s[tid]  = xv;
        cbn_s[tid] = cbn[bn * 128 + tid];
        if (STAGE == 1) {
            float cmax = __uint_as_float(*cbn_max);
            float mv = f32_unsortable(min1[bm * 128 + tid]);
            thr_s[tid] = mv + fmaf(0.003f, sqrtf(xv * cmax), 0.01f);
        }
    }

    f32x4 acc[4][4] = {};

    const int srow   = lane >> 3;          // 0..7 within 8-row group
    const int schunk = lane & 7;           // LDS chunk slot this lane fills
    const int gc     = schunk ^ srow;      // inverse-swizzled global chunk

    for (int kk = 0; kk < 256; kk += 64) {
        #pragma unroll
        for (int i = 0; i < 4; ++i) {
            int baseRow = w * 32 + i * 8;
            int row = baseRow + srow;
            const short* ga = Xh  + ((size_t)(bm * 128 + row) << 8) + kk + gc * 8;
            const short* gb = CBh + ((size_t)(bn * 128 + row) << 8) + kk + gc * 8;
            GLOAD_LDS(ga, &As[baseRow * 64]);
            GLOAD_LDS(gb, &Bs[baseRow * 64]);
        }
        __syncthreads();   // drains vmcnt -> tiles resident
        #pragma unroll
        for (int ks = 0; ks < 2; ++ks) {
            bf16x8 af[4], bfv[4];
            int kgl = ks * 4 + (lane >> 4);
            #pragma unroll
            for (int mi = 0; mi < 4; ++mi) {
                int row = wr * 64 + mi * 16 + (lane & 15);
                af[mi] = *(const bf16x8*)&As[row * 64 + ((kgl ^ (row & 7)) << 3)];
            }
            #pragma unroll
            for (int ni = 0; ni < 4; ++ni) {
                int row = wc * 64 + ni * 16 + (lane & 15);
                bfv[ni] = *(const bf16x8*)&Bs[row * 64 + ((kgl ^ (row & 7)) << 3)];
            }
            #pragma unroll
            for (int mi = 0; mi < 4; ++mi)
                #pragma unroll
                for (int ni = 0; ni < 4; ++ni)
                    acc[mi][ni] = __builtin_amdgcn_mfma_f32_16x16x32_bf16(
                        af[mi], bfv[ni], acc[mi][ni], 0, 0, 0);
        }
        __syncthreads();   // protect LDS before next overwrite
    }

    // acc[mi][ni][rg] -> row_local = wr*64+mi*16+(lane>>4)*4+rg, col_local = wc*64+ni*16+(lane&15)
    if (STAGE == 0) {
        #pragma unroll
        for (int mi = 0; mi < 4; ++mi) {
            #pragma unroll
            for (int rg = 0; rg < 4; ++rg) {
                int rl = wr * 64 + mi * 16 + (lane >> 4) * 4 + rg;
                float xxv = xx_s[rl];
                float m = 1e30f;
                #pragma unroll
                for (int ni = 0; ni < 4; ++ni) {
                    float d2a = fmaf(-2.f, acc[mi][ni][rg], xxv)
                              + cbn_s[wc * 64 + ni * 16 + (lane & 15)];
                    m = fminf(m, d2a);
                }
                #pragma unroll
                for (int d = 1; d < 16; d <<= 1) m = fminf(m, __shfl_xor(m, d, 64));
                if ((lane & 15) == 0) atomicMin(&min1[bm * 128 + rl], f32_sortable(m));
            }
        }
    } else {
        #pragma unroll
        for (int mi = 0; mi < 4; ++mi) {
            #pragma unroll
            for (int rg = 0; rg < 4; ++rg) {
                int rl = wr * 64 + mi * 16 + (lane >> 4) * 4 + rg;
                float xxv = xx_s[rl];
                float thr = thr_s[rl];
                #pragma unroll
                for (int ni = 0; ni < 4; ++ni) {
                    int cl = wc * 64 + ni * 16 + (lane & 15);
                    float d2a = fmaf(-2.f, acc[mi][ni][rg], xxv) + cbn_s[cl];
                    if (d2a <= thr) {   // rare: exact fp32 re-rank, R2's expression tree
                        int row = bm * 128 + rl;
                        int col = bn * 128 + cl;
                        const float4* xp = (const float4*)(X  + (size_t)row * COLS);
                        const float4* cp = (const float4*)(CB + (size_t)col * COLS);
                        float d = 0.f;
                        #pragma unroll 8
                        for (int q = 0; q < 64; ++q) {
                            float4 a = xp[q], b = cp[q];
                            d = fmaf(a.x, b.x, d); d = fmaf(a.y, b.y, d);
                            d = fmaf(a.z, b.z, d); d = fmaf(a.w, b.w, d);
                        }
                        float d2e = fmaf(-2.f, d, xxv) + cbn_s[cl];
                        u64 pk = ((u64)f32_sortable(d2e) << 32) | (u32)col;
                        atomicMin(&best[row], pk);
                    }
                }
            }
        }
    }
}

// ---------- kernel 3: gather e, Householder STE ----------
__global__ __launch_bounds__(256) void k_epilogue(const float* __restrict__ X,
                                                  const float* __restrict__ CB,
                                                  const u64* __restrict__ best,
                                                  float* __restrict__ Eout,
                                                  float* __restrict__ Sout) {
    int r    = blockIdx.x * 4 + (threadIdx.x >> 6);
    int lane = threadIdx.x & 63;
    int idx  = (int)(best[r] & 0xffffffffull);

    float4 xv = *reinterpret_cast<const float4*>(X  + (size_t)r   * COLS + lane * 4);
    float4 ev = *reinterpret_cast<const float4*>(CB + (size_t)idx * COLS + lane * 4);

    float xn2 = wave_sum(dot4(xv, xv));
    float en2 = wave_sum(dot4(ev, ev));
    float xn = sqrtf(xn2), en = sqrtf(en2);
    float invx = 1.f / fmaxf(xn, EPSF);
    float inve = 1.f / fmaxf(en, EPSF);

    float4 xd, ed, sd0;
    xd.x = xv.x*invx; xd.y = xv.y*invx; xd.z = xv.z*invx; xd.w = xv.w*invx;
    ed.x = ev.x*inve; ed.y = ev.y*inve; ed.z = ev.z*inve; ed.w = ev.w*inve;
    sd0.x = xd.x+ed.x; sd0.y = xd.y+ed.y; sd0.z = xd.z+ed.z; sd0.w = xd.w+ed.w;

    float sdn2 = wave_sum(dot4(sd0, sd0));
    float p1   = wave_sum(dot4(sd0, xv));
    float p2   = wave_sum(dot4(xd,  xv));
    float invs = 1.f / fmaxf(sqrtf(sdn2), EPSF);

    float csd = -2.f * invs * invs * p1;
    float ced =  2.f * p2;
    float4 rr;
    rr.x = fmaf(csd, sd0.x, fmaf(ced, ed.x, xv.x));
    rr.y = fmaf(csd, sd0.y, fmaf(ced, ed.y, xv.y));
    rr.z = fmaf(csd, sd0.z, fmaf(ced, ed.z, xv.z));
    rr.w = fmaf(csd, sd0.w, fmaf(ced, ed.w, xv.w));
    float sc = en * invx;
    float4 sv; sv.x = rr.x*sc; sv.y = rr.y*sc; sv.z = rr.z*sc; sv.w = rr.w*sc;

    *reinterpret_cast<float4*>(Eout + (size_t)r * COLS + lane * 4) = ev;
    *reinterpret_cast<float4*>(Sout + (size_t)r * COLS + lane * 4) = sv;
}

// ---------- launcher ----------
extern "C" void kernel_launch(void* const* d_in, const int* in_sizes, int n_in,
                              void* d_out, int out_size, void* d_ws, size_t ws_size,
                              hipStream_t stream) {
    const float* x  = (const float*)d_in[0];
    const float* fc = (const float*)d_in[1];
    const float* Wi = (const float*)d_in[2];
    const float* Wo = (const float*)d_in[3];

    // ws layout (~5 MB, same as R3)
    char* ws = (char*)d_ws;
    u64*   best    = (u64*)ws;                            ws += (size_t)ROWS * 8;
    float* CBws    = (float*)ws;                          ws += (size_t)Nn * COLS * 4;
    float* cbn     = (float*)ws;                          ws += (size_t)Nn * 4;
    float* xx      = (float*)ws;                          ws += (size_t)ROWS * 4;
    u32*   min1    = (u32*)ws;                            ws += (size_t)ROWS * 4;
    u32*   cbn_max = (u32*)ws;

    // bf16 copies live in d_out (128 MiB), which is only written by k_epilogue
    // at the very end: Xh = 32 MiB at offset 0, CBh = 2 MiB at offset 64 MiB.
    short* Xh  = (short*)d_out;
    short* CBh = (short*)((char*)d_out + (64u << 20));

    float* Eout = (float*)d_out;
    float* Sout = Eout + (size_t)ROWS * COLS;

    k_prep<<<ROWS / 4, 256, 0, stream>>>(x, Xh, xx, best, min1, cbn_max);
    k_codebook<<<Nn, 256, 0, stream>>>(fc, Wi, Wo, CBws, CBh, cbn, cbn_max);
    k_screen<0><<<(Nn / 128) * (ROWS / 128), 256, 0, stream>>>(Xh, CBh, x, CBws, cbn, xx, min1, best, cbn_max);
    k_screen<1><<<(Nn / 128) * (ROWS / 128), 256, 0, stream>>>(Xh, CBh, x, CBws, cbn, xx, min1, best, cbn_max);
    k_epilogue<<<ROWS / 4, 256, 0, stream>>>(x, CBws, best, Eout, Sout);
}

// Round 5
// 889.827 us; speedup vs baseline: 5.6915x; 1.1216x over previous
//
#include <hip/hip_runtime.h>
#include <hip/hip_bf16.h>
#include <stdint.h>

// Problem dims (fixed by reference)
#define Bq    8192
#define Hh    8
#define Dd    16
#define Kk    16
#define Nn    4096
#define DFf   16
#define ROWS  (Bq*Hh)          // 65536
#define COLS  (Dd*Kk)          // 256
#define EPSF  1e-6f

typedef unsigned long long u64;
typedef unsigned int u32;
typedef __attribute__((ext_vector_type(8))) short bf16x8;
typedef __attribute__((ext_vector_type(4))) float f32x4;

// async global->LDS, 16B per lane; LDS dest = wave-uniform base + lane*16
#define GLOAD_LDS(g, l) __builtin_amdgcn_global_load_lds( \
    (const __attribute__((address_space(1))) u32*)(g), \
    (__attribute__((address_space(3))) u32*)(l), 16, 0, 0)

// ---------- helpers ----------
__device__ __forceinline__ float dot4(float4 a, float4 b) {
    return fmaf(a.x, b.x, fmaf(a.y, b.y, fmaf(a.z, b.z, a.w * b.w)));
}
__device__ __forceinline__ float wave_sum(float v) {
    #pragma unroll
    for (int m = 32; m > 0; m >>= 1) v += __shfl_xor(v, m, 64);
    return v;
}
__device__ __forceinline__ u32 f32_sortable(float f) {
    u32 u = __float_as_uint(f);
    return (u & 0x80000000u) ? ~u : (u | 0x80000000u);
}
// pack 2 floats -> 2 bf16 (RNE); low 16 bits = a
__device__ __forceinline__ u32 pk2(float a, float b) {
    union { __hip_bfloat162 h; u32 u; } v;
    v.h = __float22bfloat162_rn(make_float2(a, b));
    return v.u;
}

// ---------- kernel 0: xx[r], X->bf16, init best/cbn_max ----------
__global__ __launch_bounds__(256) void k_prep(const float* __restrict__ X,
                                              short* __restrict__ Xh,
                                              float* __restrict__ xx,
                                              u64* __restrict__ best,
                                              u32* __restrict__ cbn_max) {
    int r    = blockIdx.x * 4 + (threadIdx.x >> 6);
    int lane = threadIdx.x & 63;
    float4 v = *reinterpret_cast<const float4*>(X + (size_t)r * COLS + lane * 4);
    uint2 p; p.x = pk2(v.x, v.y); p.y = pk2(v.z, v.w);
    *reinterpret_cast<uint2*>(Xh + (size_t)r * COLS + lane * 4) = p;
    float s = wave_sum(v.x*v.x + v.y*v.y + v.z*v.z + v.w*v.w);
    if (lane == 0) { xx[r] = s; best[r] = ~0ull; }
    if (blockIdx.x == 0 && threadIdx.x == 0) *cbn_max = 0u;
}

// ---------- kernel 1: codebook (fp32 + bf16) + |cb|^2 + max|cb|^2 ----------
__global__ __launch_bounds__(256) void k_codebook(const float* __restrict__ fc,
                                                  const float* __restrict__ Wi,
                                                  const float* __restrict__ Wo,
                                                  float* __restrict__ CB,
                                                  short* __restrict__ CBh,
                                                  float* __restrict__ cbn,
                                                  u32* __restrict__ cbn_max) {
    int n = blockIdx.x, tid = threadIdx.x;
    int o = tid >> 4, k = tid & 15;
    __shared__ float fcs[256], wis[256], wos[256], hs[256], sq[256];
    fcs[tid] = fc[(size_t)n * 256 + tid];
    wis[tid] = Wi[tid];
    wos[tid] = Wo[tid];
    __syncthreads();
    float hp = 0.f;
    #pragma unroll
    for (int i = 0; i < 16; ++i) hp = fmaf(wis[o*16 + i], fcs[i*16 + k], hp);
    hs[tid] = hp;
    __syncthreads();
    float h0 = hs[o * 16];
    float x3 = h0 * h0 * h0;
    float inner = 0.7978845608028654f * fmaf(0.044715f, x3, h0);
    float g = 0.5f * h0 * (1.f + tanhf(inner));
    float hg = hp * g;
    __syncthreads();
    hs[tid] = hg;
    __syncthreads();
    float cv = 0.f;
    #pragma unroll
    for (int i = 0; i < 16; ++i) cv = fmaf(wos[o*16 + i], hs[i*16 + k], cv);
    CB[(size_t)n * 256 + tid] = cv;
    { union { __hip_bfloat16 h; short s; } c; c.h = __float2bfloat16(cv);
      CBh[(size_t)n * 256 + tid] = c.s; }
    sq[tid] = cv * cv;
    __syncthreads();
    #pragma unroll
    for (int st = 128; st > 0; st >>= 1) {
        if (tid < st) sq[tid] += sq[tid + st];
        __syncthreads();
    }
    if (tid == 0) { cbn[n] = sq[0]; atomicMax(cbn_max, __float_as_uint(sq[0])); }
}

// ---------- kernel 2: FUSED tall-block screen + rerank ----------
// 512 blocks; block owns 128 rows x ALL 4096 codes. A-fragments (af[2][8],
// 64 VGPR) loaded once from Xh; B streamed twice (sweep1: per-row min in
// regs; sweep2: recompute + exact fp32 rerank of candidates) through a
// 2x16KB LDS double-buffer via global_load_lds (inverse-swizzled source).
// 2-phase pipeline: STAGE(next slice) -> ds_read+MFMA(cur) -> syncthreads.
// Buffer parity = kb&1 (static under unrolled kb loop). cbn in LDS (16KB).
__global__ __launch_bounds__(256, 2) void k_screen_fused(
        const short* __restrict__ Xh,
        const short* __restrict__ CBh,
        const float* __restrict__ X,
        const float* __restrict__ CB,
        const float* __restrict__ cbn,
        const float* __restrict__ xx,
        u64* __restrict__ best,
        const u32* __restrict__ cbn_max) {
    __shared__ __align__(16) short Bs[2][128 * 64];
    __shared__ float cbn_s[Nn];

    const int tid  = threadIdx.x;
    const int lane = tid & 63;
    const int w    = tid >> 6;
    const int bmBase = blockIdx.x * 128;

    // cbn -> LDS (all 4096 codes)
    #pragma unroll
    for (int j = 0; j < 4; ++j)
        *reinterpret_cast<float4*>(&cbn_s[tid * 16 + j * 4]) =
            *reinterpret_cast<const float4*>(&cbn[tid * 16 + j * 4]);

    // A fragments: af[mi][kc] = Xh[row][kc*32 + (lane>>4)*8 .. +8]
    bf16x8 af[2][8];
    #pragma unroll
    for (int mi = 0; mi < 2; ++mi) {
        int arow = bmBase + w * 32 + mi * 16 + (lane & 15);
        const short* ap = Xh + ((size_t)arow << 8) + (lane >> 4) * 8;
        #pragma unroll
        for (int kc = 0; kc < 8; ++kc)
            af[mi][kc] = *reinterpret_cast<const bf16x8*>(ap + kc * 32);
    }

    // per-row norms in acc layout
    float xxv[2][4];
    #pragma unroll
    for (int mi = 0; mi < 2; ++mi)
        #pragma unroll
        for (int rg = 0; rg < 4; ++rg)
            xxv[mi][rg] = xx[bmBase + w * 32 + mi * 16 + (lane >> 4) * 4 + rg];

    const float cmax = __uint_as_float(*cbn_max);

    const int srow   = lane >> 3;          // 0..7 within 8-row group
    const int schunk = lane & 7;           // LDS chunk this lane fills
    const int gc     = schunk ^ srow;      // inverse-swizzled global chunk

    // prologue: stage slice 0 (bn=0, kb=0) into Bs[0]
    #pragma unroll
    for (int i = 0; i < 4; ++i) {
        int baseRow = w * 32 + i * 8;
        const short* gb = CBh + ((size_t)(baseRow + srow) << 8) + gc * 8;
        GLOAD_LDS(gb, &Bs[0][baseRow * 64]);
    }
    __syncthreads();

    f32x4 acc[2][8];
    float rmin[2][4], thr[2][4];
    #pragma unroll
    for (int mi = 0; mi < 2; ++mi)
        #pragma unroll
        for (int rg = 0; rg < 4; ++rg) rmin[mi][rg] = 1e30f;

    for (int s4 = 0; s4 < 64; ++s4) {       // sweep = s4>>5, bn = s4&31
        const int bn = s4 & 31;
        #pragma unroll
        for (int kb = 0; kb < 4; ++kb) {     // K-slice of 64 within the 256
            // ---- stage next slice into Bs[(kb+1)&1] ----
            if (kb < 3 || s4 < 63) {
                int nbn = (kb < 3) ? bn : ((s4 + 1) & 31);
                int nkb = (kb < 3) ? (kb + 1) : 0;
                #pragma unroll
                for (int i = 0; i < 4; ++i) {
                    int baseRow = w * 32 + i * 8;
                    const short* gb = CBh + ((size_t)(nbn * 128 + baseRow + srow) << 8)
                                    + nkb * 64 + gc * 8;
                    GLOAD_LDS(gb, &Bs[(kb + 1) & 1][baseRow * 64]);
                }
            }
            // ---- compute current slice from Bs[kb&1] ----
            if (kb == 0) {
                #pragma unroll
                for (int mi = 0; mi < 2; ++mi)
                    #pragma unroll
                    for (int ni = 0; ni < 8; ++ni)
                        acc[mi][ni] = f32x4{0.f, 0.f, 0.f, 0.f};
            }
            const short* Bcur = &Bs[kb & 1][0];
            #pragma unroll
            for (int ks = 0; ks < 2; ++ks) {
                bf16x8 bfv[8];
                int kgl = ks * 4 + (lane >> 4);
                #pragma unroll
                for (int ni = 0; ni < 8; ++ni) {
                    int row = ni * 16 + (lane & 15);
                    bfv[ni] = *reinterpret_cast<const bf16x8*>(
                        &Bcur[row * 64 + ((kgl ^ (row & 7)) << 3)]);
                }
                #pragma unroll
                for (int mi = 0; mi < 2; ++mi)
                    #pragma unroll
                    for (int ni = 0; ni < 8; ++ni)
                        acc[mi][ni] = __builtin_amdgcn_mfma_f32_16x16x32_bf16(
                            af[mi][kb * 2 + ks], bfv[ni], acc[mi][ni], 0, 0, 0);
            }
            // ---- per-bn epilogue after last K-slice ----
            if (kb == 3) {
                float cb_v[8];
                #pragma unroll
                for (int ni = 0; ni < 8; ++ni)
                    cb_v[ni] = cbn_s[bn * 128 + ni * 16 + (lane & 15)];
                if (s4 < 32) {
                    // sweep 1: per-row running min of d2a
                    #pragma unroll
                    for (int mi = 0; mi < 2; ++mi)
                        #pragma unroll
                        for (int rg = 0; rg < 4; ++rg) {
                            float m = 1e30f;
                            #pragma unroll
                            for (int ni = 0; ni < 8; ++ni) {
                                float d2a = fmaf(-2.f, acc[mi][ni][rg], xxv[mi][rg]) + cb_v[ni];
                                m = fminf(m, d2a);
                            }
                            #pragma unroll
                            for (int d = 1; d < 16; d <<= 1)
                                m = fminf(m, __shfl_xor(m, d, 64));
                            rmin[mi][rg] = fminf(rmin[mi][rg], m);
                        }
                    if (s4 == 31) {   // sweep1 done -> thresholds
                        #pragma unroll
                        for (int mi = 0; mi < 2; ++mi)
                            #pragma unroll
                            for (int rg = 0; rg < 4; ++rg)
                                thr[mi][rg] = rmin[mi][rg]
                                    + fmaf(0.003f, sqrtf(xxv[mi][rg] * cmax), 0.01f);
                    }
                } else {
                    // sweep 2: candidates -> exact fp32 rerank (R2 expression tree)
                    #pragma unroll
                    for (int mi = 0; mi < 2; ++mi)
                        #pragma unroll
                        for (int rg = 0; rg < 4; ++rg) {
                            #pragma unroll
                            for (int ni = 0; ni < 8; ++ni) {
                                float d2a = fmaf(-2.f, acc[mi][ni][rg], xxv[mi][rg]) + cb_v[ni];
                                if (d2a <= thr[mi][rg]) {
                                    int row = bmBase + w * 32 + mi * 16 + (lane >> 4) * 4 + rg;
                                    int col = bn * 128 + ni * 16 + (lane & 15);
                                    const float4* xp = (const float4*)(X  + (size_t)row * COLS);
                                    const float4* cp = (const float4*)(CB + (size_t)col * COLS);
                                    float d = 0.f;
                                    #pragma unroll 8
                                    for (int q = 0; q < 64; ++q) {
                                        float4 a = xp[q], b = cp[q];
                                        d = fmaf(a.x, b.x, d); d = fmaf(a.y, b.y, d);
                                        d = fmaf(a.z, b.z, d); d = fmaf(a.w, b.w, d);
                                    }
                                    float d2e = fmaf(-2.f, d, xxv[mi][rg]) + cb_v[ni];
                                    u64 pk = ((u64)f32_sortable(d2e) << 32) | (u32)col;
                                    atomicMin(&best[row], pk);
                                }
                            }
                        }
                }
            }
            __syncthreads();   // drain stage (next buf ready) + protect cur buf
        }
    }
}

// ---------- kernel 3: gather e, Householder STE ----------
__global__ __launch_bounds__(256) void k_epilogue(const float* __restrict__ X,
                                                  const float* __restrict__ CB,
                                                  const u64* __restrict__ best,
                                                  float* __restrict__ Eout,
                                                  float* __restrict__ Sout) {
    int r    = blockIdx.x * 4 + (threadIdx.x >> 6);
    int lane = threadIdx.x & 63;
    int idx  = (int)(best[r] & 0xffffffffull);

    float4 xv = *reinterpret_cast<const float4*>(X  + (size_t)r   * COLS + lane * 4);
    float4 ev = *reinterpret_cast<const float4*>(CB + (size_t)idx * COLS + lane * 4);

    float xn2 = wave_sum(dot4(xv, xv));
    float en2 = wave_sum(dot4(ev, ev));
    float xn = sqrtf(xn2), en = sqrtf(en2);
    float invx = 1.f / fmaxf(xn, EPSF);
    float inve = 1.f / fmaxf(en, EPSF);

    float4 xd, ed, sd0;
    xd.x = xv.x*invx; xd.y = xv.y*invx; xd.z = xv.z*invx; xd.w = xv.w*invx;
    ed.x = ev.x*inve; ed.y = ev.y*inve; ed.z = ev.z*inve; ed.w = ev.w*inve;
    sd0.x = xd.x+ed.x; sd0.y = xd.y+ed.y; sd0.z = xd.z+ed.z; sd0.w = xd.w+ed.w;

    float sdn2 = wave_sum(dot4(sd0, sd0));
    float p1   = wave_sum(dot4(sd0, xv));
    float p2   = wave_sum(dot4(xd,  xv));
    float invs = 1.f / fmaxf(sqrtf(sdn2), EPSF);

    float csd = -2.f * invs * invs * p1;
    float ced =  2.f * p2;
    float4 rr;
    rr.x = fmaf(csd, sd0.x, fmaf(ced, ed.x, xv.x));
    rr.y = fmaf(csd, sd0.y, fmaf(ced, ed.y, xv.y));
    rr.z = fmaf(csd, sd0.z, fmaf(ced, ed.z, xv.z));
    rr.w = fmaf(csd, sd0.w, fmaf(ced, ed.w, xv.w));
    float sc = en * invx;
    float4 sv; sv.x = rr.x*sc; sv.y = rr.y*sc; sv.z = rr.z*sc; sv.w = rr.w*sc;

    *reinterpret_cast<float4*>(Eout + (size_t)r * COLS + lane * 4) = ev;
    *reinterpret_cast<float4*>(Sout + (size_t)r * COLS + lane * 4) = sv;
}

// ---------- launcher ----------
extern "C" void kernel_launch(void* const* d_in, const int* in_sizes, int n_in,
                              void* d_out, int out_size, void* d_ws, size_t ws_size,
                              hipStream_t stream) {
    const float* x  = (const float*)d_in[0];
    const float* fc = (const float*)d_in[1];
    const float* Wi = (const float*)d_in[2];
    const float* Wo = (const float*)d_in[3];

    // ws layout (~5 MB)
    char* ws = (char*)d_ws;
    u64*   best    = (u64*)ws;                            ws += (size_t)ROWS * 8;
    float* CBws    = (float*)ws;                          ws += (size_t)Nn * COLS * 4;
    float* cbn     = (float*)ws;                          ws += (size_t)Nn * 4;
    float* xx      = (float*)ws;                          ws += (size_t)ROWS * 4;
    u32*   cbn_max = (u32*)ws;

    // bf16 copies live in d_out (128 MiB), only overwritten by k_epilogue at
    // the very end: Xh = 32 MiB at offset 0, CBh = 2 MiB at offset 64 MiB.
    short* Xh  = (short*)d_out;
    short* CBh = (short*)((char*)d_out + (64u << 20));

    float* Eout = (float*)d_out;
    float* Sout = Eout + (size_t)ROWS * COLS;

    k_prep<<<ROWS / 4, 256, 0, stream>>>(x, Xh, xx, best, cbn_max);
    k_codebook<<<Nn, 256, 0, stream>>>(fc, Wi, Wo, CBws, CBh, cbn, cbn_max);
    k_screen_fused<<<ROWS / 128, 256, 0, stream>>>(Xh, CBh, x, CBws, cbn, xx, best, cbn_max);
    k_epilogue<<<ROWS / 4, 256, 0, stream>>>(x, CBws, best, Eout, Sout);
}